// Round 5
// baseline (164.883 us; speedup 1.0000x reference)
//
#include <hip/hip_runtime.h>
#include <hip/hip_cooperative_groups.h>
#include <math.h>

namespace cg = cooperative_groups;

#define BATCH 8
#define BN    512          // rois per frame
#define NC    37           // classes incl. background
#define NFG   36           // foreground classes
#define FD    2048         // feature dim
#define NWAVE 4            // waves per block (one NMS problem per wave)
#define NBLK  256          // blocks (= CUs); 288 problems on first 288 waves
#define ROIPB 16           // rois per block in phase 2 (8*512/256)

// Output layout (flat float32 in d_out, reference return order):
//   cls_dets  [B, NFG, BN, 5]  -> 737280 floats at offset 0
//   kept_feats[B, BN, FD]      -> 8388608 floats at offset 737280
//   keep      [B, NFG, BN]     -> 147456 floats (0/1) at offset 9125888
// d_ws: keep_t [B, BN, NFG] bytes — transposed keep, fully rewritten each call.

__global__ __launch_bounds__(256) void fused_kernel(
    const float* __restrict__ rois,       // [B,BN,5]
    const float* __restrict__ bbox_pred,  // [B,BN,4*NC]
    const float* __restrict__ scores,     // [B,BN,NC]
    const float* __restrict__ im_info,    // [B,3]
    const float* __restrict__ feats,      // [B,BN,FD]
    float* __restrict__ cls_dets,         // [B,NFG,BN,5]
    float* __restrict__ keep_out,         // [B,NFG,BN]
    float* __restrict__ out_feats,        // [B,BN,FD]
    unsigned char* __restrict__ keep_t)   // [B,BN,NFG] bytes
{
    const int wid  = threadIdx.x >> 6;
    const int lane = threadIdx.x & 63;
    const int bc   = blockIdx.x * NWAVE + wid;   // problem id, 0..1023 (valid < 288)

    __shared__ float sb[NWAVE][BN][4];    // decoded clipped boxes, original index
    __shared__ float sarea[NWAVE][BN];
    __shared__ float cscore[NWAVE][BN];
    __shared__ int   cn[NWAVE][BN];
    __shared__ float kflag[NWAVE][BN];    // 0 = not kept; score = kept
    __shared__ unsigned char srem[NWAVE][BN];
    __shared__ int s_any[ROIPB];          // phase-2 per-roi any-keep flags

    // ======================= PHASE 1: per-wave NMS ==========================
    if (bc < BATCH * NFG) {
        const int b  = bc / NFG;
        const int cc = bc % NFG;    // 0..35
        const int c  = cc + 1;      // class 1..36

        const float xmax = im_info[b * 3 + 1] - 1.0f;
        const float ymax = im_info[b * 3 + 0] - 1.0f;
        const unsigned long long lmask_lt = (lane == 0) ? 0ull : ((1ull << lane) - 1ull);

        // ---- prefetch everything (independent loads, one latency round) ----
        float  sc[8];
        float4 bp[8];               // bbox_pred[..., 4c:4c+4] (16B-aligned)
        float  rx1[8], ry1[8], rx2[8], ry2[8];
#pragma unroll
        for (int r = 0; r < 8; ++r) {
            const int n = r * 64 + lane;
            sc[r] = scores[(size_t)(b * BN + n) * NC + c];
            bp[r] = *(const float4*)(bbox_pred + (size_t)(b * BN + n) * (4 * NC) + 4 * c);
            const float* rr = rois + (size_t)(b * BN + n) * 5;
            rx1[r] = rr[1]; ry1[r] = rr[2]; rx2[r] = rr[3]; ry2[r] = rr[4];
            kflag[wid][n] = 0.0f;
        }

        // ---- decode + clip ALL boxes --------------------------------------
#pragma unroll
        for (int r = 0; r < 8; ++r) {
            const int n = r * 64 + lane;
            const float w  = rx2[r] - rx1[r];
            const float h  = ry2[r] - ry1[r];
            const float cx = rx1[r] + 0.5f * w;
            const float cy = ry1[r] + 0.5f * h;
            const float px = (bp[r].x * 0.1f) * w + cx;
            const float py = (bp[r].y * 0.1f) * h + cy;
            const float pw = expf(bp[r].z * 0.2f) * w;
            const float ph = expf(bp[r].w * 0.2f) * h;
            const float bx1 = fminf(fmaxf(px - 0.5f * pw, 0.0f), xmax);
            const float by1 = fminf(fmaxf(py - 0.5f * ph, 0.0f), ymax);
            const float bx2 = fminf(fmaxf(px + 0.5f * pw, 0.0f), xmax);
            const float by2 = fminf(fmaxf(py + 0.5f * ph, 0.0f), ymax);
            sb[wid][n][0] = bx1; sb[wid][n][1] = by1;
            sb[wid][n][2] = bx2; sb[wid][n][3] = by2;
            sarea[wid][n] = (bx2 - bx1) * (by2 - by1);
        }

        // ---- compact valid (score > 0.1) ----------------------------------
        int base = 0;
#pragma unroll
        for (int r = 0; r < 8; ++r) {
            const int n = r * 64 + lane;
            const bool valid = sc[r] > 0.1f;
            const unsigned long long m = __ballot(valid);
            if (valid) {
                const int pos = base + __popcll(m & lmask_lt);
                cscore[wid][pos] = sc[r];
                cn[wid][pos] = n;
            }
            base += __popcll(m);
        }
        const int V = base;   // wave-uniform
        __builtin_amdgcn_wave_barrier();

        if (V <= 64) {
            // ---- fast path: register bitonic sort + masked greedy ----------
            float key; int id;
            if (lane < V) { key = cscore[wid][lane]; id = cn[wid][lane]; }
            else          { key = -INFINITY;         id = BN + lane; }
#pragma unroll
            for (int k = 2; k <= 64; k <<= 1) {
#pragma unroll
                for (int j = k >> 1; j > 0; j >>= 1) {
                    const float ok = __shfl_xor(key, j);
                    const int   oi = __shfl_xor(id, j);
                    const bool is_lower   = (lane & j) == 0;
                    const bool dir_desc   = (lane & k) == 0;
                    const bool mine_first = (key > ok) || (key == ok && id < oi);
                    bool take = mine_first ^ is_lower;
                    if (!dir_desc) take = !take;
                    if (take) { key = ok; id = oi; }
                }
            }
            float x1 = 0, y1 = 0, x2 = 0, y2 = 0, ar = 0;
            if (lane < V) {
                x1 = sb[wid][id][0]; y1 = sb[wid][id][1];
                x2 = sb[wid][id][2]; y2 = sb[wid][id][3];
                ar = sarea[wid][id];
            }
            // pipelined: column mask = which earlier boxes would suppress me
            unsigned long long colmask = 0;
            for (int i = 0; i < V; ++i) {
                const float ax1 = __shfl(x1, i);
                const float ay1 = __shfl(y1, i);
                const float ax2 = __shfl(x2, i);
                const float ay2 = __shfl(y2, i);
                const float aar = __shfl(ar, i);
                const float ix1 = fmaxf(ax1, x1);
                const float iy1 = fmaxf(ay1, y1);
                const float ix2 = fminf(ax2, x2);
                const float iy2 = fminf(ay2, y2);
                const float iw = fmaxf(ix2 - ix1, 0.0f);
                const float ih = fmaxf(iy2 - iy1, 0.0f);
                const float inter = iw * ih;
                const float iou = inter / (aar + ar - inter + 1e-9f);
                if ((iou > 0.4f) && (i < lane)) colmask |= (1ull << i);
            }
            // serial resolve: one ballot per surviving box
            unsigned long long rem = (V == 64) ? ~0ull : ((1ull << V) - 1ull);
            for (int i = 0; i < V; ++i) {
                if (!((rem >> i) & 1ull)) continue;    // wave-uniform
                rem &= ~__ballot((colmask >> i) & 1ull);
            }
            if (lane < V && ((rem >> lane) & 1ull)) {
                kflag[wid][id] = key;
            }
        } else {
            // ---- generic path (V > 64): LDS bitonic + LDS greedy -----------
            int P = 64; while (P < V) P <<= 1;
            for (int i = lane; i < P; i += 64) {
                if (i >= V) { cscore[wid][i] = -INFINITY; cn[wid][i] = BN + i; }
                srem[wid][i] = (i < V) ? 1 : 0;
            }
            __builtin_amdgcn_wave_barrier();
            for (int k = 2; k <= P; k <<= 1) {
                for (int j = k >> 1; j > 0; j >>= 1) {
                    __builtin_amdgcn_wave_barrier();
                    for (int i = lane; i < P; i += 64) {
                        const int ixj = i ^ j;
                        if (ixj > i) {
                            const float ka = cscore[wid][i], kb = cscore[wid][ixj];
                            const int   ia = cn[wid][i],     ib = cn[wid][ixj];
                            const bool a_first = (ka > kb) || (ka == kb && ia < ib);
                            const bool up = ((i & k) == 0);
                            if (up ? !a_first : a_first) {
                                cscore[wid][i] = kb; cscore[wid][ixj] = ka;
                                cn[wid][i] = ib;     cn[wid][ixj] = ia;
                            }
                        }
                    }
                }
            }
            __builtin_amdgcn_wave_barrier();
            for (int i = 0; i < V; ++i) {
                __builtin_amdgcn_wave_barrier();
                if (!srem[wid][i]) continue;
                const int   ni  = cn[wid][i];
                const float ax1 = sb[wid][ni][0], ay1 = sb[wid][ni][1];
                const float ax2 = sb[wid][ni][2], ay2 = sb[wid][ni][3];
                const float aar = sarea[wid][ni];
                for (int jj = lane; jj < V; jj += 64) {
                    if (jj > i && srem[wid][jj]) {
                        const int nj = cn[wid][jj];
                        const float ix1 = fmaxf(ax1, sb[wid][nj][0]);
                        const float iy1 = fmaxf(ay1, sb[wid][nj][1]);
                        const float ix2 = fminf(ax2, sb[wid][nj][2]);
                        const float iy2 = fminf(ay2, sb[wid][nj][3]);
                        const float iw = fmaxf(ix2 - ix1, 0.0f);
                        const float ih = fmaxf(iy2 - iy1, 0.0f);
                        const float inter = iw * ih;
                        const float iou = inter / (aar + sarea[wid][nj] - inter + 1e-9f);
                        if (iou > 0.4f) srem[wid][jj] = 0;
                    }
                }
            }
            __builtin_amdgcn_wave_barrier();
            for (int i = lane; i < V; i += 64) {
                if (srem[wid][i]) kflag[wid][cn[wid][i]] = cscore[wid][i];
            }
        }
        __builtin_amdgcn_wave_barrier();

        // ---- outputs: every (n) written exactly once -----------------------
        const size_t rowbase = (size_t)(b * NFG + cc) * BN;
#pragma unroll
        for (int r = 0; r < 8; ++r) {
            const int n = r * 64 + lane;
            const float s = kflag[wid][n];
            const bool kept = s > 0.0f;
            keep_out[rowbase + n] = kept ? 1.0f : 0.0f;
            keep_t[(size_t)(b * BN + n) * NFG + cc] = kept ? 1 : 0;
            float* cd = cls_dets + (rowbase + n) * 5;
            cd[0] = kept ? sb[wid][n][0] : 0.0f;
            cd[1] = kept ? sb[wid][n][1] : 0.0f;
            cd[2] = kept ? sb[wid][n][2] : 0.0f;
            cd[3] = kept ? sb[wid][n][3] : 0.0f;
            cd[4] = kept ? s : 0.0f;
        }
    }

    // ======================= grid-wide barrier ==============================
    cg::this_grid().sync();

    // ======================= PHASE 2: feature masking =======================
    // Each block owns ROIPB consecutive rois -> one contiguous 128 KB segment.
    if (threadIdx.x < ROIPB) s_any[threadIdx.x] = 0;
    __syncthreads();
    if (threadIdx.x < ROIPB * 9) {       // 36 bytes = 9 dwords per roi
        const int rl = threadIdx.x / 9;
        const int dw = threadIdx.x % 9;
        const int roi = blockIdx.x * ROIPB + rl;
        const unsigned int w = *(const unsigned int*)(keep_t + (size_t)roi * NFG + 4 * dw);
        if (w != 0u) atomicOr(&s_any[rl], 1);
    }
    __syncthreads();

    const size_t fbase = (size_t)blockIdx.x * ROIPB * FD;
    const float4* src = (const float4*)(feats + fbase);
    float4*       dst = (float4*)(out_feats + fbase);
    const float4 z = make_float4(0.f, 0.f, 0.f, 0.f);
#pragma unroll
    for (int i = 0; i < (ROIPB * FD / 4) / 256; ++i) {   // 32 iterations
        const int idx = i * 256 + threadIdx.x;
        const int rl  = i >> 1;            // 512 float4 per roi, 256 per iter -> uniform
        if (s_any[rl]) dst[idx] = src[idx];
        else           dst[idx] = z;
    }
}

extern "C" void kernel_launch(void* const* d_in, const int* in_sizes, int n_in,
                              void* d_out, int out_size, void* d_ws, size_t ws_size,
                              hipStream_t stream) {
    const float* rois      = (const float*)d_in[0];  // [8,512,5]
    const float* bbox_pred = (const float*)d_in[1];  // [8,512,148]
    const float* scores    = (const float*)d_in[2];  // [8,512,37]
    const float* im_info   = (const float*)d_in[3];  // [8,3]
    const float* feats     = (const float*)d_in[4];  // [8,512,2048]

    float* out        = (float*)d_out;
    float* cls_dets   = out;                                     // 737280
    float* kept_feats = out + (size_t)BATCH * NFG * BN * 5;      // 8388608
    float* keep_out   = kept_feats + (size_t)BATCH * BN * FD;    // 147456

    unsigned char* keep_t = (unsigned char*)d_ws;  // [B,BN,NFG] bytes, fully rewritten

    void* args[] = {
        (void*)&rois, (void*)&bbox_pred, (void*)&scores, (void*)&im_info,
        (void*)&feats, (void*)&cls_dets, (void*)&keep_out, (void*)&kept_feats,
        (void*)&keep_t
    };
    hipLaunchCooperativeKernel((const void*)fused_kernel, dim3(NBLK), dim3(256),
                               args, 0, stream);
}

// Round 6
// 109.718 us; speedup vs baseline: 1.5028x; 1.5028x over previous
//
#include <hip/hip_runtime.h>
#include <math.h>

#define BATCH 8
#define BN    512          // rois per frame
#define NC    37           // classes incl. background
#define NFG   36           // foreground classes
#define FD    2048         // feature dim
#define NWAVE 4            // NMS problems (waves) per nms block
#define NMSB  ((BATCH * NFG) / NWAVE)   // 72 nms blocks
#define RPCB  4            // rois per copy block
#define COPYB ((BATCH * BN) / RPCB)     // 1024 copy blocks
#define RPFB  8            // rois per fixup block
#define FIXB  ((BATCH * BN) / RPFB)     // 512 fixup blocks

// Output layout (flat float32 in d_out, reference return order):
//   cls_dets  [B, NFG, BN, 5]  -> 737280 floats at offset 0
//   kept_feats[B, BN, FD]      -> 8388608 floats at offset 737280
//   keep      [B, NFG, BN]     -> 147456 floats (0/1) at offset 9125888
// d_ws: keep_t [B, BN, NFG] bytes — transposed keep, fully rewritten each call.

// ---- Kernel 1: blocks [0,72): per-wave NMS (bit-identical to round 4);
//      blocks [72,1096): unconditional feats->kept_feats copy (overlaps NMS).
__global__ __launch_bounds__(256) void nms_copy_kernel(
    const float* __restrict__ rois,       // [B,BN,5]
    const float* __restrict__ bbox_pred,  // [B,BN,4*NC]
    const float* __restrict__ scores,     // [B,BN,NC]
    const float* __restrict__ im_info,    // [B,3]
    const float* __restrict__ feats,      // [B,BN,FD]
    float* __restrict__ cls_dets,         // [B,NFG,BN,5]
    float* __restrict__ keep_out,         // [B,NFG,BN]
    float* __restrict__ out_feats,        // [B,BN,FD]
    unsigned char* __restrict__ keep_t)   // [B,BN,NFG] bytes
{
    __shared__ float sb[NWAVE][BN][4];
    __shared__ float sarea[NWAVE][BN];
    __shared__ float cscore[NWAVE][BN];
    __shared__ int   cn[NWAVE][BN];
    __shared__ float kflag[NWAVE][BN];
    __shared__ unsigned char srem[NWAVE][BN];

    if (blockIdx.x >= NMSB) {
        // ---------------- copy path: 4 rois = 8192 floats, coalesced --------
        const int cb = blockIdx.x - NMSB;
        const float4* src = (const float4*)(feats + (size_t)cb * RPCB * FD);
        float4*       dst = (float4*)(out_feats + (size_t)cb * RPCB * FD);
#pragma unroll
        for (int i = 0; i < (RPCB * FD / 4) / 256; ++i) {   // 8 iterations
            const int idx = i * 256 + threadIdx.x;
            dst[idx] = src[idx];
        }
        return;
    }

    // ---------------- NMS path: one (batch, fg-class) problem per wave ------
    const int wid  = threadIdx.x >> 6;
    const int lane = threadIdx.x & 63;
    const int bc   = blockIdx.x * NWAVE + wid;   // 0..287
    const int b    = bc / NFG;
    const int cc   = bc % NFG;    // 0..35
    const int c    = cc + 1;      // class 1..36

    const float xmax = im_info[b * 3 + 1] - 1.0f;
    const float ymax = im_info[b * 3 + 0] - 1.0f;
    const unsigned long long lmask_lt = (lane == 0) ? 0ull : ((1ull << lane) - 1ull);

    // ---- prefetch everything (independent loads, one latency round) --------
    float  sc[8];
    float4 bp[8];                 // bbox_pred[..., 4c:4c+4] (16B-aligned)
    float  rx1[8], ry1[8], rx2[8], ry2[8];
#pragma unroll
    for (int r = 0; r < 8; ++r) {
        const int n = r * 64 + lane;
        sc[r] = scores[(size_t)(b * BN + n) * NC + c];
        bp[r] = *(const float4*)(bbox_pred + (size_t)(b * BN + n) * (4 * NC) + 4 * c);
        const float* rr = rois + (size_t)(b * BN + n) * 5;
        rx1[r] = rr[1]; ry1[r] = rr[2]; rx2[r] = rr[3]; ry2[r] = rr[4];
        kflag[wid][n] = 0.0f;
    }

    // ---- decode + clip ALL boxes -------------------------------------------
#pragma unroll
    for (int r = 0; r < 8; ++r) {
        const int n = r * 64 + lane;
        const float w  = rx2[r] - rx1[r];
        const float h  = ry2[r] - ry1[r];
        const float cx = rx1[r] + 0.5f * w;
        const float cy = ry1[r] + 0.5f * h;
        const float px = (bp[r].x * 0.1f) * w + cx;
        const float py = (bp[r].y * 0.1f) * h + cy;
        const float pw = expf(bp[r].z * 0.2f) * w;
        const float ph = expf(bp[r].w * 0.2f) * h;
        const float bx1 = fminf(fmaxf(px - 0.5f * pw, 0.0f), xmax);
        const float by1 = fminf(fmaxf(py - 0.5f * ph, 0.0f), ymax);
        const float bx2 = fminf(fmaxf(px + 0.5f * pw, 0.0f), xmax);
        const float by2 = fminf(fmaxf(py + 0.5f * ph, 0.0f), ymax);
        sb[wid][n][0] = bx1; sb[wid][n][1] = by1;
        sb[wid][n][2] = bx2; sb[wid][n][3] = by2;
        sarea[wid][n] = (bx2 - bx1) * (by2 - by1);
    }

    // ---- compact valid (score > 0.1) ---------------------------------------
    int base = 0;
#pragma unroll
    for (int r = 0; r < 8; ++r) {
        const int n = r * 64 + lane;
        const bool valid = sc[r] > 0.1f;
        const unsigned long long m = __ballot(valid);
        if (valid) {
            const int pos = base + __popcll(m & lmask_lt);
            cscore[wid][pos] = sc[r];
            cn[wid][pos] = n;
        }
        base += __popcll(m);
    }
    const int V = base;   // wave-uniform
    __builtin_amdgcn_wave_barrier();

    if (V <= 64) {
        // -------- fast path: register bitonic sort + masked greedy ----------
        float key; int id;
        if (lane < V) { key = cscore[wid][lane]; id = cn[wid][lane]; }
        else          { key = -INFINITY;         id = BN + lane; }
#pragma unroll
        for (int k = 2; k <= 64; k <<= 1) {
#pragma unroll
            for (int j = k >> 1; j > 0; j >>= 1) {
                const float ok = __shfl_xor(key, j);
                const int   oi = __shfl_xor(id, j);
                const bool is_lower   = (lane & j) == 0;
                const bool dir_desc   = (lane & k) == 0;
                const bool mine_first = (key > ok) || (key == ok && id < oi);
                bool take = mine_first ^ is_lower;
                if (!dir_desc) take = !take;
                if (take) { key = ok; id = oi; }
            }
        }
        float x1 = 0, y1 = 0, x2 = 0, y2 = 0, ar = 0;
        if (lane < V) {
            x1 = sb[wid][id][0]; y1 = sb[wid][id][1];
            x2 = sb[wid][id][2]; y2 = sb[wid][id][3];
            ar = sarea[wid][id];
        }
        // pipelined: column mask = which earlier boxes would suppress me
        unsigned long long colmask = 0;
        for (int i = 0; i < V; ++i) {
            const float ax1 = __shfl(x1, i);
            const float ay1 = __shfl(y1, i);
            const float ax2 = __shfl(x2, i);
            const float ay2 = __shfl(y2, i);
            const float aar = __shfl(ar, i);
            const float ix1 = fmaxf(ax1, x1);
            const float iy1 = fmaxf(ay1, y1);
            const float ix2 = fminf(ax2, x2);
            const float iy2 = fminf(ay2, y2);
            const float iw = fmaxf(ix2 - ix1, 0.0f);
            const float ih = fmaxf(iy2 - iy1, 0.0f);
            const float inter = iw * ih;
            const float iou = inter / (aar + ar - inter + 1e-9f);
            if ((iou > 0.4f) && (i < lane)) colmask |= (1ull << i);
        }
        // serial resolve: one ballot per surviving box
        unsigned long long rem = (V == 64) ? ~0ull : ((1ull << V) - 1ull);
        for (int i = 0; i < V; ++i) {
            if (!((rem >> i) & 1ull)) continue;    // wave-uniform
            rem &= ~__ballot((colmask >> i) & 1ull);
        }
        if (lane < V && ((rem >> lane) & 1ull)) {
            kflag[wid][id] = key;
        }
    } else {
        // -------- generic path (V > 64): LDS bitonic + LDS greedy -----------
        int P = 64; while (P < V) P <<= 1;
        for (int i = lane; i < P; i += 64) {
            if (i >= V) { cscore[wid][i] = -INFINITY; cn[wid][i] = BN + i; }
            srem[wid][i] = (i < V) ? 1 : 0;
        }
        __builtin_amdgcn_wave_barrier();
        for (int k = 2; k <= P; k <<= 1) {
            for (int j = k >> 1; j > 0; j >>= 1) {
                __builtin_amdgcn_wave_barrier();
                for (int i = lane; i < P; i += 64) {
                    const int ixj = i ^ j;
                    if (ixj > i) {
                        const float ka = cscore[wid][i], kb = cscore[wid][ixj];
                        const int   ia = cn[wid][i],     ib = cn[wid][ixj];
                        const bool a_first = (ka > kb) || (ka == kb && ia < ib);
                        const bool up = ((i & k) == 0);
                        if (up ? !a_first : a_first) {
                            cscore[wid][i] = kb; cscore[wid][ixj] = ka;
                            cn[wid][i] = ib;     cn[wid][ixj] = ia;
                        }
                    }
                }
            }
        }
        __builtin_amdgcn_wave_barrier();
        for (int i = 0; i < V; ++i) {
            __builtin_amdgcn_wave_barrier();
            if (!srem[wid][i]) continue;
            const int   ni  = cn[wid][i];
            const float ax1 = sb[wid][ni][0], ay1 = sb[wid][ni][1];
            const float ax2 = sb[wid][ni][2], ay2 = sb[wid][ni][3];
            const float aar = sarea[wid][ni];
            for (int jj = lane; jj < V; jj += 64) {
                if (jj > i && srem[wid][jj]) {
                    const int nj = cn[wid][jj];
                    const float ix1 = fmaxf(ax1, sb[wid][nj][0]);
                    const float iy1 = fmaxf(ay1, sb[wid][nj][1]);
                    const float ix2 = fminf(ax2, sb[wid][nj][2]);
                    const float iy2 = fminf(ay2, sb[wid][nj][3]);
                    const float iw = fmaxf(ix2 - ix1, 0.0f);
                    const float ih = fmaxf(iy2 - iy1, 0.0f);
                    const float inter = iw * ih;
                    const float iou = inter / (aar + sarea[wid][nj] - inter + 1e-9f);
                    if (iou > 0.4f) srem[wid][jj] = 0;
                }
            }
        }
        __builtin_amdgcn_wave_barrier();
        for (int i = lane; i < V; i += 64) {
            if (srem[wid][i]) kflag[wid][cn[wid][i]] = cscore[wid][i];
        }
    }
    __builtin_amdgcn_wave_barrier();

    // ---- outputs: every (n) written exactly once ---------------------------
    const size_t rowbase = (size_t)(b * NFG + cc) * BN;
#pragma unroll
    for (int r = 0; r < 8; ++r) {
        const int n = r * 64 + lane;
        const float s = kflag[wid][n];
        const bool kept = s > 0.0f;
        keep_out[rowbase + n] = kept ? 1.0f : 0.0f;
        keep_t[(size_t)(b * BN + n) * NFG + cc] = kept ? 1 : 0;
        float* cd = cls_dets + (rowbase + n) * 5;
        cd[0] = kept ? sb[wid][n][0] : 0.0f;
        cd[1] = kept ? sb[wid][n][1] : 0.0f;
        cd[2] = kept ? sb[wid][n][2] : 0.0f;
        cd[3] = kept ? sb[wid][n][3] : 0.0f;
        cd[4] = kept ? s : 0.0f;
    }
}

// ---- Kernel 2: zero out_feats rows for rois with NO kept class. ------------
// Most rois are kept -> most blocks read 36 B of L2-hot flags and exit.
__global__ __launch_bounds__(256) void fixup_kernel(
    const unsigned char* __restrict__ keep_t,   // [B,BN,NFG] bytes
    float* __restrict__ out_feats)              // [B,BN,FD]
{
    __shared__ int s_any[RPFB];
    if (threadIdx.x < RPFB) s_any[threadIdx.x] = 0;
    __syncthreads();
    if (threadIdx.x < RPFB * 9) {       // 36 bytes = 9 dwords per roi
        const int rl = threadIdx.x / 9;
        const int dw = threadIdx.x % 9;
        const int roi = blockIdx.x * RPFB + rl;
        const unsigned int w = *(const unsigned int*)(keep_t + (size_t)roi * NFG + 4 * dw);
        if (w != 0u) atomicOr(&s_any[rl], 1);
    }
    __syncthreads();

    float4* dst = (float4*)(out_feats + (size_t)blockIdx.x * RPFB * FD);
    const float4 z = make_float4(0.f, 0.f, 0.f, 0.f);
#pragma unroll
    for (int i = 0; i < (RPFB * FD / 4) / 256; ++i) {   // 16 iterations
        const int idx = i * 256 + threadIdx.x;
        const int rl  = idx >> 9;          // 512 float4 per roi -> block-uniform
        if (!s_any[rl]) dst[idx] = z;
    }
}

extern "C" void kernel_launch(void* const* d_in, const int* in_sizes, int n_in,
                              void* d_out, int out_size, void* d_ws, size_t ws_size,
                              hipStream_t stream) {
    const float* rois      = (const float*)d_in[0];  // [8,512,5]
    const float* bbox_pred = (const float*)d_in[1];  // [8,512,148]
    const float* scores    = (const float*)d_in[2];  // [8,512,37]
    const float* im_info   = (const float*)d_in[3];  // [8,3]
    const float* feats     = (const float*)d_in[4];  // [8,512,2048]

    float* out        = (float*)d_out;
    float* cls_dets   = out;                                     // 737280
    float* kept_feats = out + (size_t)BATCH * NFG * BN * 5;      // 8388608
    float* keep_out   = kept_feats + (size_t)BATCH * BN * FD;    // 147456

    unsigned char* keep_t = (unsigned char*)d_ws;  // [B,BN,NFG] bytes, fully rewritten

    nms_copy_kernel<<<NMSB + COPYB, 256, 0, stream>>>(
        rois, bbox_pred, scores, im_info, feats,
        cls_dets, keep_out, kept_feats, keep_t);
    fixup_kernel<<<FIXB, 256, 0, stream>>>(keep_t, kept_feats);
}